// Round 6
// baseline (299.975 us; speedup 1.0000x reference)
//
#include <hip/hip_runtime.h>
#include <math.h>

#define Bg   64
#define Nn   1024
#define Dd   256
#define EPG  16384               // edges per graph
#define EPB  4096                // edges per block (4 blocks/graph)
#define NT   65536
#define Kk   512

// d_out float offsets
#define OFF_PERM  16777216
#define OFF_PCOM  16809984
#define OFF_SOFT  16842752

// ws byte offsets
#define WS_BAR    0                        // 64 B barrier counter (memset 0)
#define WS_H0     256
#define WS_SFLAT  (WS_H0 + NT * 4)
#define WS_GPART  (WS_SFLAT + NT * 4)      // 256 blocks * 256 cols
#define WS_DO4    (WS_GPART + 256 * 256 * 4)
#define WS_DI4    (WS_DO4 + 4 * NT * 4)
#define WS_AGG4   (WS_DI4 + 4 * NT * 4)
#define WS_REDM   (WS_AGG4 + 4 * NT * 4)   // 256 per-block partials
#define WS_REDS   (WS_REDM + 256 * 4)
#define WS_PERMI  (WS_REDS + 256 * 4)
#define WS_PCOMI  (WS_PERMI + 32768 * 4)

__device__ __forceinline__ void gridbar(int* ctr, int target) {
    __syncthreads();
    if (threadIdx.x == 0) {
        __threadfence();
        __hip_atomic_fetch_add(ctr, 1, __ATOMIC_RELEASE, __HIP_MEMORY_SCOPE_AGENT);
        while (__hip_atomic_load(ctr, __ATOMIC_ACQUIRE, __HIP_MEMORY_SCOPE_AGENT) < target)
            __builtin_amdgcn_s_sleep(8);
        __threadfence();
    }
    __syncthreads();
}

// 256 blocks x 1024 threads, 1 block/CU, persistent with 4 grid barriers.
__global__ __launch_bounds__(1024, 4) void k_all(
        const float* __restrict__ f, const float* __restrict__ W,
        const int* __restrict__ src, const int* __restrict__ dst,
        const int* __restrict__ label, const float* __restrict__ bias,
        const float* __restrict__ lw, const float* __restrict__ lb,
        float* __restrict__ out, int* __restrict__ bar,
        float* __restrict__ h0, float* __restrict__ sflat,
        float* __restrict__ gpart, int* __restrict__ do4, int* __restrict__ di4,
        float* __restrict__ agg4, float* __restrict__ redM, float* __restrict__ redS,
        int* __restrict__ permI, int* __restrict__ pcomI) {
    __shared__ unsigned epk[EPB];            // 16 KB, persists P1->P2
    __shared__ float scol[4096];             // 16 KB, P1 colsums / P3 score stash
    __shared__ int   sdo[Nn];                // 4 KB
    __shared__ int   sdi[Nn];                // 4 KB
    __shared__ float shn[Nn];                // 4 KB
    __shared__ float sagg[Nn];               // 4 KB
    __shared__ float cpart[2048];            // 8 KB
    __shared__ float c0s[Dd], c1s[Dd];       // 2 KB, persists P2->P3
    __shared__ unsigned long long sk[1024];  // 8 KB (P4)
    __shared__ int   sflag[1024];            // 4 KB (P4)
    __shared__ int   swave[8];
    __shared__ float sred[16];

    int b = blockIdx.x, t = threadIdx.x;
    int lane = t & 63, w = t >> 6;           // wave 0..15
    int g = b >> 2, sl = b & 3;
    const float4* f4 = (const float4*)f;

    //================ P1: edges pass A + feature colsum + h0 ================
    sdo[t] = 0; sdi[t] = 0;
    int4 ss = ((const int4*)(src + g * EPG + sl * EPB))[t];   // 4 edges/thread
    int4 dd = ((const int4*)(dst + g * EPG + sl * EPB))[t];
    __syncthreads();
    {
        // feature rows b*256 .. +255; wave w -> 16 rows
        float4 wv = ((const float4*)W)[lane];
        float4 cs = make_float4(0.f, 0.f, 0.f, 0.f);
        int rbase = b * 256 + w * 16;
        for (int r = 0; r < 16; ++r) {
            float4 v = f4[(size_t)(rbase + r) * 64 + lane];
            cs.x += v.x; cs.y += v.y; cs.z += v.z; cs.w += v.w;
            float d = v.x * wv.x + v.y * wv.y + v.z * wv.z + v.w * wv.w;
            for (int o = 32; o > 0; o >>= 1) d += __shfl_xor(d, o);
            if (lane == 0) h0[rbase + r] = d;
        }
        ((float4*)scol)[w * 64 + lane] = cs;
    }
    {
        int s0 = ss.x & 1023, s1 = ss.y & 1023, s2 = ss.z & 1023, s3 = ss.w & 1023;
        int e0 = dd.x & 1023, e1 = dd.y & 1023, e2 = dd.z & 1023, e3 = dd.w & 1023;
        uint4 pk;
        pk.x = (unsigned)(s0 | (e0 << 16));
        pk.y = (unsigned)(s1 | (e1 << 16));
        pk.z = (unsigned)(s2 | (e2 << 16));
        pk.w = (unsigned)(s3 | (e3 << 16));
        ((uint4*)epk)[t] = pk;
        atomicAdd(&sdo[s0], 1); atomicAdd(&sdo[s1], 1);
        atomicAdd(&sdo[s2], 1); atomicAdd(&sdo[s3], 1);
        atomicAdd(&sdi[e0], 1); atomicAdd(&sdi[e1], 1);
        atomicAdd(&sdi[e2], 1); atomicAdd(&sdi[e3], 1);
    }
    __syncthreads();
    if (t < 256) {
        float s = 0.f;
        for (int q = 0; q < 16; ++q) s += scol[q * 256 + t];
        gpart[b * 256 + t] = s;
    }
    do4[sl * NT + g * Nn + t] = sdo[t];
    di4[sl * NT + g * Nn + t] = sdi[t];
    gridbar(bar, 256);

    //================ P2: centers (redundant) + scatter ================
    {
        int q = t >> 8, c = t & 255;
        int n1 = 0;
        for (int gg = 0; gg < Bg; ++gg) n1 += label[gg];
        float s0 = 0.f, s1 = 0.f;
        for (int bb2 = q * 64; bb2 < q * 64 + 64; ++bb2) {
            float v = gpart[bb2 * 256 + c];
            if (label[bb2 >> 2]) s1 += v; else s0 += v;
        }
        cpart[q * 256 + c] = s0;
        cpart[1024 + q * 256 + c] = s1;
        __syncthreads();
        if (t < 256) {
            float a0 = cpart[t] + cpart[256 + t] + cpart[512 + t] + cpart[768 + t];
            float a1 = cpart[1024 + t] + cpart[1280 + t] + cpart[1536 + t] + cpart[1792 + t];
            float fn1 = fmaxf((float)n1, 1.f);
            float fn0 = fmaxf((float)(Bg - n1), 1.f);
            c0s[t] = (a0 / (float)Nn) / fn0;
            c1s[t] = (a1 / (float)Nn) / fn1;
        }
    }
    {
        int node = g * Nn + t;
        int dg = do4[node] + do4[NT + node] + do4[2 * NT + node] + do4[3 * NT + node];
        if (dg < 1) dg = 1;
        shn[t] = h0[node] / sqrtf((float)dg);
        sagg[t] = 0.f;
    }
    __syncthreads();
    {
        uint4 pk = ((const uint4*)epk)[t];
        atomicAdd(&sagg[pk.x >> 16], shn[pk.x & 0xFFFF]);
        atomicAdd(&sagg[pk.y >> 16], shn[pk.y & 0xFFFF]);
        atomicAdd(&sagg[pk.z >> 16], shn[pk.z & 0xFFFF]);
        atomicAdd(&sagg[pk.w >> 16], shn[pk.w & 0xFFFF]);
    }
    __syncthreads();
    agg4[sl * NT + g * Nn + t] = sagg[t];
    gridbar(bar, 512);

    //================ P3: score + per-block softmax partials ================
    {
        float4 a = ((const float4*)c0s)[lane];
        float4 bb4 = ((const float4*)c1s)[lane];
        float sgn = label[g] ? 1.f : -1.f;
        float blw0 = lw[0], blw1 = lw[1], blb = lb[0], bbias = bias[0];
        int rbase = b * 256 + w * 16;
        for (int r = 0; r < 16; ++r) {
            int node = rbase + r;
            float4 v = f4[(size_t)node * 64 + lane];
            float dx, acc0, acc1;
            dx = v.x - a.x;   acc0  = dx * dx;
            dx = v.y - a.y;   acc0 += dx * dx;
            dx = v.z - a.z;   acc0 += dx * dx;
            dx = v.w - a.w;   acc0 += dx * dx;
            dx = v.x - bb4.x; acc1  = dx * dx;
            dx = v.y - bb4.y; acc1 += dx * dx;
            dx = v.z - bb4.z; acc1 += dx * dx;
            dx = v.w - bb4.w; acc1 += dx * dx;
            for (int o = 32; o > 0; o >>= 1) {
                acc0 += __shfl_xor(acc0, o);
                acc1 += __shfl_xor(acc1, o);
            }
            if (lane == 0) {
                float sdist = (sqrtf(acc0) - sqrtf(acc1)) * sgn;
                float agg = agg4[node] + agg4[NT + node] + agg4[2 * NT + node] + agg4[3 * NT + node];
                int dg = di4[node] + di4[NT + node] + di4[2 * NT + node] + di4[3 * NT + node];
                if (dg < 1) dg = 1;
                float sg = agg / sqrtf((float)dg) + bbias;
                float sc = sg * blw0 + sdist * blw1 + blb;
                sflat[node] = sc;
                scol[w * 16 + r] = sc;
            }
        }
        __syncthreads();
        if (t < 256) {
            float m = scol[t];
            for (int o = 32; o > 0; o >>= 1) m = fmaxf(m, __shfl_xor(m, o));
            if (lane == 0) sred[t >> 6] = m;
        }
        __syncthreads();
        if (t == 0) sred[8] = fmaxf(fmaxf(sred[0], sred[1]), fmaxf(sred[2], sred[3]));
        __syncthreads();
        float M = sred[8];
        if (t < 256) {
            float e = expf(scol[t] - M);
            for (int o = 32; o > 0; o >>= 1) e += __shfl_xor(e, o);
            if (lane == 0) sred[4 + (t >> 6)] = e;
        }
        __syncthreads();
        if (t == 0) { redM[b] = M; redS[b] = sred[4] + sred[5] + sred[6] + sred[7]; }
    }
    gridbar(bar, 768);

    //================ P4: topk (blocks 0..63, one graph each) ================
    if (b < Bg) {
        int gg = b;
        float v = sflat[gg * Nn + t];
        unsigned u = __float_as_uint(v);
        unsigned od = u ^ ((u >> 31) ? 0xFFFFFFFFu : 0x80000000u);
        sk[t] = ((unsigned long long)od << 32) | (unsigned)(1023 - t);
        __syncthreads();
        for (int k = 2; k <= 1024; k <<= 1) {
            for (int j = k >> 1; j > 0; j >>= 1) {
                if (t < 512) {
                    int l = ((t & ~(j - 1)) << 1) | (t & (j - 1));
                    int r = l | j;
                    unsigned long long a = sk[l], bk = sk[r];
                    bool up = ((l & k) == 0);
                    if ((a < bk) == up) { sk[l] = bk; sk[r] = a; }
                }
                __syncthreads();
            }
        }
        sflag[t] = 1;
        __syncthreads();
        if (t < 512) {
            int loc = 1023 - (int)(sk[t] & 0xFFFFFFFFu);
            sflag[loc] = 0;
            int gi = gg * Nn + loc;
            permI[gg * Kk + t] = gi;
            out[OFF_PERM + gg * Kk + t] = (float)gi;
        }
        __syncthreads();
        int f0 = 0, f1 = 0, inc = 0, fsum = 0;
        if (t < 512) {
            f0 = sflag[2 * t]; f1 = sflag[2 * t + 1];
            fsum = f0 + f1;
            inc = fsum;
            for (int o = 1; o < 64; o <<= 1) {
                int y = __shfl_up(inc, o);
                if (lane >= o) inc += y;
            }
            if (lane == 63) swave[w] = inc;
        }
        __syncthreads();
        if (t < 8) {
            int a = swave[t];
            for (int o = 1; o < 8; o <<= 1) {
                int y = __shfl_up(a, o);
                if (t >= o) a += y;
            }
            swave[t] = a;
        }
        __syncthreads();
        if (t < 512) {
            int basep = ((w > 0) ? swave[w - 1] : 0) + (inc - fsum);
            if (f0) {
                int gi = gg * Nn + 2 * t;
                pcomI[gg * Kk + basep] = gi;
                out[OFF_PCOM + gg * Kk + basep] = (float)gi;
            }
            if (f1) {
                int pos = basep + f0;
                int gi = gg * Nn + 2 * t + 1;
                pcomI[gg * Kk + pos] = gi;
                out[OFF_PCOM + gg * Kk + pos] = (float)gi;
            }
        }
    }
    gridbar(bar, 1024);

    //================ P5: softmax combine + write + gather ================
    {
        if (t < 256) {
            float m = redM[t];
            for (int o = 32; o > 0; o >>= 1) m = fmaxf(m, __shfl_xor(m, o));
            if (lane == 0) sred[t >> 6] = m;
        }
        __syncthreads();
        if (t == 0) sred[8] = fmaxf(fmaxf(sred[0], sred[1]), fmaxf(sred[2], sred[3]));
        __syncthreads();
        float M = sred[8];
        if (t < 256) {
            float s = redS[t] * expf(redM[t] - M);
            for (int o = 32; o > 0; o >>= 1) s += __shfl_xor(s, o);
            if (lane == 0) sred[4 + (t >> 6)] = s;
        }
        __syncthreads();
        if (t == 0) sred[9] = sred[4] + sred[5] + sred[6] + sred[7];
        __syncthreads();
        float S = sred[9];
        if (t < 256) {
            int node = b * 256 + t;
            out[OFF_SOFT + node] = expf(sflat[node] - M) / S;
        }
        for (int r = 0; r < 16; ++r) {
            int j = b * 256 + w * 16 + r;
            int row = (j < 32768) ? permI[j] : pcomI[j - 32768];
            float tv = tanhf(sflat[row]);
            float4 v = f4[(size_t)row * 64 + lane];
            ((float4*)out)[(size_t)j * 64 + lane] =
                make_float4(v.x * tv, v.y * tv, v.z * tv, v.w * tv);
        }
    }
}

extern "C" void kernel_launch(void* const* d_in, const int* in_sizes, int n_in,
                              void* d_out, int out_size, void* d_ws, size_t ws_size,
                              hipStream_t stream) {
    const float* feature = (const float*)d_in[0];
    const int*   src     = (const int*)d_in[1];
    const int*   dst     = (const int*)d_in[2];
    const int*   label   = (const int*)d_in[3];
    const float* W       = (const float*)d_in[4];
    const float* bias    = (const float*)d_in[5];
    const float* lw      = (const float*)d_in[6];
    const float* lb      = (const float*)d_in[7];
    float* out = (float*)d_out;
    char*  ws  = (char*)d_ws;

    int*   bar   = (int*)(ws + WS_BAR);
    float* h0    = (float*)(ws + WS_H0);
    float* sflat = (float*)(ws + WS_SFLAT);
    float* gpart = (float*)(ws + WS_GPART);
    int*   do4   = (int*)(ws + WS_DO4);
    int*   di4   = (int*)(ws + WS_DI4);
    float* agg4  = (float*)(ws + WS_AGG4);
    float* redM  = (float*)(ws + WS_REDM);
    float* redS  = (float*)(ws + WS_REDS);
    int*   permI = (int*)(ws + WS_PERMI);
    int*   pcomI = (int*)(ws + WS_PCOMI);

    hipMemsetAsync(ws + WS_BAR, 0, 64, stream);
    k_all<<<256, 1024, 0, stream>>>(feature, W, src, dst, label, bias, lw, lb,
                                    out, bar, h0, sflat, gpart, do4, di4, agg4,
                                    redM, redS, permI, pcomI);
}